// Round 1
// baseline (356.845 us; speedup 1.0000x reference)
//
#include <hip/hip_runtime.h>

// GlobalChannelAttention: B=16, C=256, N=H*W=4096
//
// Pipeline (all TN-form GEMMs: C[M,N] = sum_k A[m][k]*B[n][k], both operands
// stored [out-dim][K] with K contiguous, matching MFMA A/B fragment layout):
//   1. prep:  x[b][c][n] f32 -> Xh/Xl (bf16 hi/lo, [b][c][n]) + Xth (bf16, [b][n][c])
//             + xsum[b][c] = sum_n x  (for exact bias handling)
//   2. Gram:  G[b] = X X^T  (K=4096, split-K=8, bf16x3, f32 partials -> reduce)
//   3. T2  = W2 * G      (bf16x3, G symmetric so TN works directly)
//      L   = T2 * W3^T   (bf16x3)  == Q K^T logits (biases fixed up in softmax)
//   4. global softmax over 65536 logits/batch -> WTh[d][c] = weight[c][d] (bf16)
//   5. Vt  = Xt * W1^T + b1   (plain bf16; [n][c] layout == V^T)
//   6. out = WT * Vt^T        (plain bf16) -> f32 d_out
//
// Precision: logit chain uses hi+lo bf16 split with 3 MFMAs (err ~2^-17 rel);
// V/out chain tolerates plain bf16 (0.4% rel -> ~0.02 abs vs threshold 0.089).

typedef unsigned short u16;
typedef __attribute__((ext_vector_type(8))) short short8;
typedef __attribute__((ext_vector_type(4))) float floatx4;

__device__ __forceinline__ u16 f2b(float f) {
  union { float f; unsigned int u; } v; v.f = f;
  unsigned int u = v.u;
  return (u16)((u + 0x7fffu + ((u >> 16) & 1u)) >> 16);  // RNE
}
__device__ __forceinline__ float b2f(u16 h) {
  union { unsigned int u; float f; } v; v.u = ((unsigned int)h) << 16;
  return v.f;
}

// ---------------- W split: w1 -> hi only; w2,w3 -> hi/lo ----------------
__global__ void split_w_kernel(const float* __restrict__ w1, const float* __restrict__ w2,
                               const float* __restrict__ w3,
                               u16* __restrict__ W1h, u16* __restrict__ W2h, u16* __restrict__ W2l,
                               u16* __restrict__ W3h, u16* __restrict__ W3l) {
  int i = blockIdx.x * 256 + threadIdx.x;  // 0 .. 3*65536
  int mat = i >> 16, e = i & 0xffff;
  if (mat == 0) {
    W1h[e] = f2b(w1[e]);
  } else if (mat == 1) {
    float f = w2[e]; u16 h = f2b(f);
    W2h[e] = h; W2l[e] = f2b(f - b2f(h));
  } else {
    float f = w3[e]; u16 h = f2b(f);
    W3h[e] = h; W3l[e] = f2b(f - b2f(h));
  }
}

// ---------------- x prep: split + transpose + column sums ----------------
__global__ void prep_x_kernel(const float* __restrict__ x, u16* __restrict__ Xh,
                              u16* __restrict__ Xl, u16* __restrict__ Xth,
                              float* __restrict__ xsum) {
  __shared__ float tile[32][33];
  const int b = blockIdx.z, c0 = blockIdx.y * 32, n0 = blockIdx.x * 32;
  const int tx = threadIdx.x, ty = threadIdx.y;
#pragma unroll
  for (int i = 0; i < 4; ++i) {
    int c = c0 + ty + i * 8;
    long gi = ((long)(b * 256 + c)) * 4096 + n0 + tx;
    float v = x[gi];
    tile[ty + i * 8][tx] = v;
    u16 h = f2b(v);
    Xh[gi] = h;
    Xl[gi] = f2b(v - b2f(h));
  }
  __syncthreads();
#pragma unroll
  for (int i = 0; i < 4; ++i) {
    int n = n0 + ty + i * 8;
    Xth[((long)(b * 4096 + n)) * 256 + c0 + tx] = f2b(tile[tx][ty + i * 8]);
  }
  if (ty == 0) {
    float s = 0.f;
#pragma unroll
    for (int j = 0; j < 32; ++j) s += tile[tx][j];
    atomicAdd(&xsum[b * 256 + c0 + tx], s);
  }
}

// ---------------- TN GEMM core: 128x128 tile, BK=32, 4 waves ----------------
// EPI: 0 = f32 store, 1 = bf16 hi/lo store, 2 = bf16 hi store
template <bool X3, int EPI, bool COLBIAS>
__global__ __launch_bounds__(256) void gemm_tn(
    const u16* __restrict__ Ah, const u16* __restrict__ Al,
    const u16* __restrict__ Bh, const u16* __restrict__ Bl,
    long aBatch, long bBatch, long oBatch, long oSplit,
    int M, int N, int K, int kChunk, int tilesM,
    float* __restrict__ outF, u16* __restrict__ outH, u16* __restrict__ outL,
    const float* __restrict__ bias) {
  constexpr int LR = 40;  // row stride in shorts (+8 pad breaks bank conflicts)
  __shared__ u16 smem[(X3 ? 4 : 2) * 128 * LR];
  u16* lAh = smem;
  u16* lBh = smem + 128 * LR;
  u16* lAl = X3 ? (smem + 2 * 128 * LR) : nullptr;
  u16* lBl = X3 ? (smem + 3 * 128 * LR) : nullptr;

  const int b = blockIdx.z, s = blockIdx.y;
  const int tm = blockIdx.x % tilesM, tn = blockIdx.x / tilesM;
  const u16* Ahb = Ah + (long)b * aBatch;
  const u16* Bhb = Bh + (long)b * bBatch;
  const u16* Alb = X3 ? (Al + (long)b * aBatch) : nullptr;
  const u16* Blb = X3 ? (Bl + (long)b * bBatch) : nullptr;

  const int t = threadIdx.x;
  const int lane = t & 63, wave = t >> 6;
  const int quad = lane >> 4, l16 = lane & 15;
  const int wm = (wave & 1) * 64, wn = (wave >> 1) * 64;

  const int srow = t >> 2;        // 0..63
  const int scol = (t & 3) * 8;   // 0,8,16,24

  floatx4 acc[4][4] = {};

  const int k0 = s * kChunk;
  for (int kb = 0; kb < kChunk; kb += 32) {
    const long kk = k0 + kb;
    __syncthreads();
#pragma unroll
    for (int h = 0; h < 2; ++h) {
      const int r = srow + h * 64;
      *(uint4*)(lAh + r * LR + scol) = *(const uint4*)(Ahb + (long)(tm * 128 + r) * K + kk + scol);
      *(uint4*)(lBh + r * LR + scol) = *(const uint4*)(Bhb + (long)(tn * 128 + r) * K + kk + scol);
      if (X3) {
        *(uint4*)(lAl + r * LR + scol) = *(const uint4*)(Alb + (long)(tm * 128 + r) * K + kk + scol);
        *(uint4*)(lBl + r * LR + scol) = *(const uint4*)(Blb + (long)(tn * 128 + r) * K + kk + scol);
      }
    }
    __syncthreads();
    short8 afh[4], bfh[4], afl[4], bfl[4];
#pragma unroll
    for (int i = 0; i < 4; ++i) {
      afh[i] = *(const short8*)(lAh + (wm + i * 16 + l16) * LR + quad * 8);
      bfh[i] = *(const short8*)(lBh + (wn + i * 16 + l16) * LR + quad * 8);
      if (X3) {
        afl[i] = *(const short8*)(lAl + (wm + i * 16 + l16) * LR + quad * 8);
        bfl[i] = *(const short8*)(lBl + (wn + i * 16 + l16) * LR + quad * 8);
      }
    }
#pragma unroll
    for (int i = 0; i < 4; ++i)
#pragma unroll
      for (int j = 0; j < 4; ++j) {
        acc[i][j] = __builtin_amdgcn_mfma_f32_16x16x32_bf16(afh[i], bfh[j], acc[i][j], 0, 0, 0);
        if (X3) {
          acc[i][j] = __builtin_amdgcn_mfma_f32_16x16x32_bf16(afh[i], bfl[j], acc[i][j], 0, 0, 0);
          acc[i][j] = __builtin_amdgcn_mfma_f32_16x16x32_bf16(afl[i], bfh[j], acc[i][j], 0, 0, 0);
        }
      }
  }

  const long obase = (long)b * oBatch + (long)s * oSplit;
#pragma unroll
  for (int i = 0; i < 4; ++i) {
    const int mb = tm * 128 + wm + i * 16 + quad * 4;
#pragma unroll
    for (int j = 0; j < 4; ++j) {
      const int n = tn * 128 + wn + j * 16 + l16;
      const float bv = COLBIAS ? bias[n] : 0.0f;
#pragma unroll
      for (int r = 0; r < 4; ++r) {
        const float v = acc[i][j][r] + bv;
        const long idx = obase + (long)(mb + r) * N + n;
        if (EPI == 0) {
          outF[idx] = v;
        } else if (EPI == 1) {
          u16 h = f2b(v);
          outH[idx] = h;
          outL[idx] = f2b(v - b2f(h));
        } else {
          outH[idx] = f2b(v);
        }
      }
    }
  }
}

// ---------------- Gram split-K reduction + hi/lo split ----------------
__global__ void reduce_g_kernel(const float* __restrict__ Gp, u16* __restrict__ Gh,
                                u16* __restrict__ Gl) {
  int e = blockIdx.x * 256 + threadIdx.x;  // over 16*65536
  float s = 0.f;
#pragma unroll
  for (int i = 0; i < 8; ++i) s += Gp[(long)i * 1048576 + e];
  u16 h = f2b(s);
  Gh[e] = h;
  Gl[e] = f2b(s - b2f(h));
}

// ---------------- global softmax (per batch over 256x256), write WT bf16 ----
__global__ __launch_bounds__(1024) void softmax_kernel(
    const float* __restrict__ L, const float* __restrict__ xsum,
    const float* __restrict__ w2, const float* __restrict__ w3,
    const float* __restrict__ b2, const float* __restrict__ b3,
    u16* __restrict__ WTh) {
  __shared__ float s2[256], s3[256], red[16];
  const int b = blockIdx.x, t = threadIdx.x;
  // s2[a] = sum_n q0[a,n] = w2[a,:]·xsum ; s3[d] = w3[d,:]·xsum (exact bias fixup)
  if (t < 512) {
    const float* wm = (t < 256) ? w2 : w3;
    int a = t & 255;
    float s = 0.f;
    for (int c = 0; c < 256; ++c) s += wm[a * 256 + c] * xsum[b * 256 + c];
    if (t < 256) s2[a] = s; else s3[a] = s;
  }
  __syncthreads();
  const float* Lb = L + (long)b * 65536;
  float lc[64];
  float m = -3.4e38f;
#pragma unroll
  for (int i = 0; i < 64; ++i) {
    int fw = t + i * 1024;           // fw = d*256 + a  (write-coalesced order)
    int d = fw >> 8, a = fw & 255;
    float v = Lb[a * 256 + d] + b2[a] * s3[d] + b3[d] * s2[a] + 4096.f * b2[a] * b3[d];
    lc[i] = v;
    m = fmaxf(m, v);
  }
  const int wid = t >> 6, lane = t & 63;
  for (int o = 32; o; o >>= 1) m = fmaxf(m, __shfl_xor(m, o));
  if (lane == 0) red[wid] = m;
  __syncthreads();
  if (t == 0) {
    float mm = red[0];
    for (int i = 1; i < 16; ++i) mm = fmaxf(mm, red[i]);
    red[0] = mm;
  }
  __syncthreads();
  m = red[0];
  float s = 0.f;
#pragma unroll
  for (int i = 0; i < 64; ++i) s += __expf(lc[i] - m);
  for (int o = 32; o; o >>= 1) s += __shfl_xor(s, o);
  __syncthreads();
  if (lane == 0) red[wid] = s;
  __syncthreads();
  if (t == 0) {
    float ss = 0.f;
    for (int i = 0; i < 16; ++i) ss += red[i];
    red[0] = ss;
  }
  __syncthreads();
  const float inv = 1.0f / red[0];
  u16* Wb = WTh + (long)b * 65536;
#pragma unroll
  for (int i = 0; i < 64; ++i) {
    int fw = t + i * 1024;  // WT[d][a] = weight[a][d]
    Wb[fw] = f2b(__expf(lc[i] - m) * inv);
  }
}

extern "C" void kernel_launch(void* const* d_in, const int* in_sizes, int n_in,
                              void* d_out, int out_size, void* d_ws, size_t ws_size,
                              hipStream_t stream) {
  const float* x  = (const float*)d_in[0];
  const float* w1 = (const float*)d_in[1];
  const float* b1 = (const float*)d_in[2];
  const float* w2 = (const float*)d_in[3];
  const float* b2 = (const float*)d_in[4];
  const float* w3 = (const float*)d_in[5];
  const float* b3 = (const float*)d_in[6];
  float* out = (float*)d_out;

  char* ws = (char*)d_ws;
  size_t off = 0;
  auto alloc = [&](size_t bytes) {
    void* p = ws + off;
    off += (bytes + 255) & ~(size_t)255;
    return p;
  };
  const size_t BIG = 16ull * 4096 * 256 * 2;          // 32 MiB bf16
  u16* Xh   = (u16*)alloc(BIG);
  u16* Xl   = (u16*)alloc(BIG);
  u16* Xth  = (u16*)alloc(BIG);
  u16* Vth  = (u16*)alloc(BIG);
  float* Gp = (float*)alloc(8ull * 16 * 65536 * 4);   // 32 MiB split-K partials
  u16* Gh   = (u16*)alloc(16ull * 65536 * 2);
  u16* Gl   = (u16*)alloc(16ull * 65536 * 2);
  u16* T2h  = (u16*)alloc(16ull * 65536 * 2);
  u16* T2l  = (u16*)alloc(16ull * 65536 * 2);
  float* Lb = (float*)alloc(16ull * 65536 * 4);
  u16* WTh  = (u16*)alloc(16ull * 65536 * 2);
  u16* W1h  = (u16*)alloc(65536 * 2);
  u16* W2h  = (u16*)alloc(65536 * 2);
  u16* W2l  = (u16*)alloc(65536 * 2);
  u16* W3h  = (u16*)alloc(65536 * 2);
  u16* W3l  = (u16*)alloc(65536 * 2);
  float* xsum = (float*)alloc(16 * 256 * 4);

  hipMemsetAsync(xsum, 0, 16 * 256 * 4, stream);
  split_w_kernel<<<768, 256, 0, stream>>>(w1, w2, w3, W1h, W2h, W2l, W3h, W3l);
  prep_x_kernel<<<dim3(128, 8, 16), dim3(32, 8), 0, stream>>>(x, Xh, Xl, Xth, xsum);

  // G partials = X X^T, K=4096, split-K 8x512. M=N=256.
  gemm_tn<true, 0, false><<<dim3(4, 8, 16), 256, 0, stream>>>(
      Xh, Xl, Xh, Xl, 1048576, 1048576, 65536, 1048576,
      256, 256, 4096, 512, 2, Gp, nullptr, nullptr, nullptr);
  reduce_g_kernel<<<4096, 256, 0, stream>>>(Gp, Gh, Gl);

  // T2 = W2 * G  (G symmetric -> TN ok). M=N=K=256.
  gemm_tn<true, 1, false><<<dim3(4, 1, 16), 256, 0, stream>>>(
      W2h, W2l, Gh, Gl, 0, 65536, 65536, 0,
      256, 256, 256, 256, 2, nullptr, T2h, T2l, nullptr);
  // L = T2 * W3^T.
  gemm_tn<true, 0, false><<<dim3(4, 1, 16), 256, 0, stream>>>(
      T2h, T2l, W3h, W3l, 65536, 0, 65536, 0,
      256, 256, 256, 256, 2, Lb, nullptr, nullptr, nullptr);

  softmax_kernel<<<16, 1024, 0, stream>>>(Lb, xsum, w2, w3, b2, b3, WTh);

  // Vt = Xt * W1^T + b1 (col bias over output channel). M=4096, N=256, K=256.
  gemm_tn<false, 2, true><<<dim3(64, 1, 16), 256, 0, stream>>>(
      Xth, nullptr, W1h, nullptr, 1048576, 0, 1048576, 0,
      4096, 256, 256, 256, 32, nullptr, Vth, nullptr, b1);
  // out = WT * Vt^T. M=256, N=4096, K=256 -> d_out [b][d][n].
  gemm_tn<false, 0, false><<<dim3(64, 1, 16), 256, 0, stream>>>(
      WTh, nullptr, Vth, nullptr, 65536, 1048576, 1048576, 0,
      256, 4096, 256, 256, 2, out, nullptr, nullptr, nullptr);
}

// Round 2
// 309.001 us; speedup vs baseline: 1.1548x; 1.1548x over previous
//
#include <hip/hip_runtime.h>

// GlobalChannelAttention: B=16, C=256, N=H*W=4096
//
// Pipeline (all TN-form GEMMs: C[M,N] = sum_k A[m][k]*B[n][k], both operands
// stored [out-dim][K] with K contiguous, matching MFMA A/B fragment layout):
//   1. prep:  x[b][c][n] f32 -> Xh/Xl (bf16 hi/lo, [b][c][n]) + Xth (bf16, [b][n][c])
//             + xsum[b][c] = sum_n x  (for exact bias handling)
//   2. Gram:  G[b] = X X^T  (K=4096, split-K=8, bf16x3, f32 partials -> reduce)
//   3. T3  = W3 * G      (bf16x3, G symmetric so TN works directly)
//      Lt  = T3 * W2^T   (bf16x3)  == (Q K^T)^T logits, i.e. Lt[d][a]=L[a][d]
//      (transposed on purpose: softmax then reads AND writes at the same flat
//       index -> fully coalesced, no transpose anywhere)
//   4. global softmax over 65536 logits/batch, 3-pass parallel:
//      pass1 block-local (m,s), pass2 combine, pass3 write WT bf16
//   5. Vt  = Xt * W1^T + b1   (plain bf16; [n][c] layout == V^T)
//   6. out = WT * Vt^T        (plain bf16) -> f32 d_out
//
// Precision: logit chain uses hi+lo bf16 split with 3 MFMAs (err ~2^-17 rel);
// V/out chain tolerates plain bf16 (0.4% rel -> ~0.02 abs vs threshold 0.089).

typedef unsigned short u16;
typedef __attribute__((ext_vector_type(8))) short short8;
typedef __attribute__((ext_vector_type(4))) float floatx4;

__device__ __forceinline__ u16 f2b(float f) {
  union { float f; unsigned int u; } v; v.f = f;
  unsigned int u = v.u;
  return (u16)((u + 0x7fffu + ((u >> 16) & 1u)) >> 16);  // RNE
}
__device__ __forceinline__ float b2f(u16 h) {
  union { unsigned int u; float f; } v; v.u = ((unsigned int)h) << 16;
  return v.f;
}

// ---------------- W split: w1 -> hi only; w2,w3 -> hi/lo ----------------
__global__ void split_w_kernel(const float* __restrict__ w1, const float* __restrict__ w2,
                               const float* __restrict__ w3,
                               u16* __restrict__ W1h, u16* __restrict__ W2h, u16* __restrict__ W2l,
                               u16* __restrict__ W3h, u16* __restrict__ W3l) {
  int i = blockIdx.x * 256 + threadIdx.x;  // 0 .. 3*65536
  int mat = i >> 16, e = i & 0xffff;
  if (mat == 0) {
    W1h[e] = f2b(w1[e]);
  } else if (mat == 1) {
    float f = w2[e]; u16 h = f2b(f);
    W2h[e] = h; W2l[e] = f2b(f - b2f(h));
  } else {
    float f = w3[e]; u16 h = f2b(f);
    W3h[e] = h; W3l[e] = f2b(f - b2f(h));
  }
}

// ---------------- x prep: split + transpose + column sums ----------------
__global__ void prep_x_kernel(const float* __restrict__ x, u16* __restrict__ Xh,
                              u16* __restrict__ Xl, u16* __restrict__ Xth,
                              float* __restrict__ xsum) {
  __shared__ float tile[32][33];
  const int b = blockIdx.z, c0 = blockIdx.y * 32, n0 = blockIdx.x * 32;
  const int tx = threadIdx.x, ty = threadIdx.y;
#pragma unroll
  for (int i = 0; i < 4; ++i) {
    int c = c0 + ty + i * 8;
    long gi = ((long)(b * 256 + c)) * 4096 + n0 + tx;
    float v = x[gi];
    tile[ty + i * 8][tx] = v;
    u16 h = f2b(v);
    Xh[gi] = h;
    Xl[gi] = f2b(v - b2f(h));
  }
  __syncthreads();
#pragma unroll
  for (int i = 0; i < 4; ++i) {
    int n = n0 + ty + i * 8;
    Xth[((long)(b * 4096 + n)) * 256 + c0 + tx] = f2b(tile[tx][ty + i * 8]);
  }
  if (ty == 0) {
    float s = 0.f;
#pragma unroll
    for (int j = 0; j < 32; ++j) s += tile[tx][j];
    atomicAdd(&xsum[b * 256 + c0 + tx], s);
  }
}

// ---------------- TN GEMM core: 128x128 tile, BK=32, 4 waves ----------------
// EPI: 0 = f32 store, 1 = bf16 hi/lo store, 2 = bf16 hi store
template <bool X3, int EPI, bool COLBIAS>
__global__ __launch_bounds__(256) void gemm_tn(
    const u16* __restrict__ Ah, const u16* __restrict__ Al,
    const u16* __restrict__ Bh, const u16* __restrict__ Bl,
    long aBatch, long bBatch, long oBatch, long oSplit,
    int M, int N, int K, int kChunk, int tilesM,
    float* __restrict__ outF, u16* __restrict__ outH, u16* __restrict__ outL,
    const float* __restrict__ bias) {
  constexpr int LR = 40;  // row stride in shorts (+8 pad breaks bank conflicts)
  __shared__ u16 smem[(X3 ? 4 : 2) * 128 * LR];
  u16* lAh = smem;
  u16* lBh = smem + 128 * LR;
  u16* lAl = X3 ? (smem + 2 * 128 * LR) : nullptr;
  u16* lBl = X3 ? (smem + 3 * 128 * LR) : nullptr;

  const int b = blockIdx.z, s = blockIdx.y;
  const int tm = blockIdx.x % tilesM, tn = blockIdx.x / tilesM;
  const u16* Ahb = Ah + (long)b * aBatch;
  const u16* Bhb = Bh + (long)b * bBatch;
  const u16* Alb = X3 ? (Al + (long)b * aBatch) : nullptr;
  const u16* Blb = X3 ? (Bl + (long)b * bBatch) : nullptr;

  const int t = threadIdx.x;
  const int lane = t & 63, wave = t >> 6;
  const int quad = lane >> 4, l16 = lane & 15;
  const int wm = (wave & 1) * 64, wn = (wave >> 1) * 64;

  const int srow = t >> 2;        // 0..63
  const int scol = (t & 3) * 8;   // 0,8,16,24

  floatx4 acc[4][4] = {};

  const int k0 = s * kChunk;
  for (int kb = 0; kb < kChunk; kb += 32) {
    const long kk = k0 + kb;
    __syncthreads();
#pragma unroll
    for (int h = 0; h < 2; ++h) {
      const int r = srow + h * 64;
      *(uint4*)(lAh + r * LR + scol) = *(const uint4*)(Ahb + (long)(tm * 128 + r) * K + kk + scol);
      *(uint4*)(lBh + r * LR + scol) = *(const uint4*)(Bhb + (long)(tn * 128 + r) * K + kk + scol);
      if (X3) {
        *(uint4*)(lAl + r * LR + scol) = *(const uint4*)(Alb + (long)(tm * 128 + r) * K + kk + scol);
        *(uint4*)(lBl + r * LR + scol) = *(const uint4*)(Blb + (long)(tn * 128 + r) * K + kk + scol);
      }
    }
    __syncthreads();
    short8 afh[4], bfh[4], afl[4], bfl[4];
#pragma unroll
    for (int i = 0; i < 4; ++i) {
      afh[i] = *(const short8*)(lAh + (wm + i * 16 + l16) * LR + quad * 8);
      bfh[i] = *(const short8*)(lBh + (wn + i * 16 + l16) * LR + quad * 8);
      if (X3) {
        afl[i] = *(const short8*)(lAl + (wm + i * 16 + l16) * LR + quad * 8);
        bfl[i] = *(const short8*)(lBl + (wn + i * 16 + l16) * LR + quad * 8);
      }
    }
#pragma unroll
    for (int i = 0; i < 4; ++i)
#pragma unroll
      for (int j = 0; j < 4; ++j) {
        acc[i][j] = __builtin_amdgcn_mfma_f32_16x16x32_bf16(afh[i], bfh[j], acc[i][j], 0, 0, 0);
        if (X3) {
          acc[i][j] = __builtin_amdgcn_mfma_f32_16x16x32_bf16(afh[i], bfl[j], acc[i][j], 0, 0, 0);
          acc[i][j] = __builtin_amdgcn_mfma_f32_16x16x32_bf16(afl[i], bfh[j], acc[i][j], 0, 0, 0);
        }
      }
  }

  const long obase = (long)b * oBatch + (long)s * oSplit;
#pragma unroll
  for (int i = 0; i < 4; ++i) {
    const int mb = tm * 128 + wm + i * 16 + quad * 4;
#pragma unroll
    for (int j = 0; j < 4; ++j) {
      const int n = tn * 128 + wn + j * 16 + l16;
      const float bv = COLBIAS ? bias[n] : 0.0f;
#pragma unroll
      for (int r = 0; r < 4; ++r) {
        const float v = acc[i][j][r] + bv;
        const long idx = obase + (long)(mb + r) * N + n;
        if (EPI == 0) {
          outF[idx] = v;
        } else if (EPI == 1) {
          u16 h = f2b(v);
          outH[idx] = h;
          outL[idx] = f2b(v - b2f(h));
        } else {
          outH[idx] = f2b(v);
        }
      }
    }
  }
}

// ---------------- Gram split-K reduction + hi/lo split ----------------
__global__ void reduce_g_kernel(const float* __restrict__ Gp, u16* __restrict__ Gh,
                                u16* __restrict__ Gl) {
  int e = blockIdx.x * 256 + threadIdx.x;  // over 16*65536
  float s = 0.f;
#pragma unroll
  for (int i = 0; i < 8; ++i) s += Gp[(long)i * 1048576 + e];
  u16 h = f2b(s);
  Gh[e] = h;
  Gl[e] = f2b(s - b2f(h));
}

// ---------------- bias prep: s2[b][a]=w2[a,:]·xsum[b], s3 likewise --------
__global__ __launch_bounds__(512) void bias_prep_kernel(
    const float* __restrict__ w2, const float* __restrict__ w3,
    const float* __restrict__ xsum, float* __restrict__ S2, float* __restrict__ S3) {
  __shared__ float xs[256];
  const int b = blockIdx.x, t = threadIdx.x;
  if (t < 256) xs[t] = xsum[b * 256 + t];
  __syncthreads();
  const float* wm = (t < 256) ? w2 : w3;
  const int a = t & 255;
  float s = 0.f;
#pragma unroll 4
  for (int c = 0; c < 256; ++c) s += wm[a * 256 + c] * xs[c];
  if (t < 256) S2[b * 256 + a] = s;
  else         S3[b * 256 + a] = s;
}

// ---------------- softmax pass1: per-block (max, sumexp) ------------------
// Lt layout: flat fw = d*256 + a per batch. Bias fixup:
//   v = Lt[fw] + b2[a]*(s3[d] + N*b3[d]) + b3[d]*s2[a]
__global__ __launch_bounds__(256) void softmax_pass1(
    const float* __restrict__ Lt, const float* __restrict__ S2, const float* __restrict__ S3,
    const float* __restrict__ b2, const float* __restrict__ b3,
    float* __restrict__ bm, float* __restrict__ bs) {
  __shared__ float ls2[256], lb2[256];
  __shared__ float redm[4], reds[4];
  const int b = blockIdx.y, blk = blockIdx.x, t = threadIdx.x;
  ls2[t] = S2[b * 256 + t];
  lb2[t] = b2[t];
  __syncthreads();
  const int fw0 = blk * 2048 + t * 8;
  const int d = fw0 >> 8, a0 = fw0 & 255;
  const float c1 = b3[d];                      // scalar-ish (uniform per 32 lanes)
  const float c0 = S3[b * 256 + d] + 4096.f * c1;
  const long base = (long)b * 65536 + fw0;
  float4 v0 = *(const float4*)(Lt + base);
  float4 v1 = *(const float4*)(Lt + base + 4);
  float v[8] = {v0.x, v0.y, v0.z, v0.w, v1.x, v1.y, v1.z, v1.w};
  float m = -3.4e38f;
#pragma unroll
  for (int i = 0; i < 8; ++i) {
    v[i] += lb2[a0 + i] * c0 + c1 * ls2[a0 + i];
    m = fmaxf(m, v[i]);
  }
  for (int o = 32; o; o >>= 1) m = fmaxf(m, __shfl_xor(m, o));
  const int wid = t >> 6, lane = t & 63;
  if (lane == 0) redm[wid] = m;
  __syncthreads();
  const float bmax = fmaxf(fmaxf(redm[0], redm[1]), fmaxf(redm[2], redm[3]));
  float s = 0.f;
#pragma unroll
  for (int i = 0; i < 8; ++i) s += __expf(v[i] - bmax);
  for (int o = 32; o; o >>= 1) s += __shfl_xor(s, o);
  if (lane == 0) reds[wid] = s;
  __syncthreads();
  if (t == 0) {
    bm[b * 32 + blk] = bmax;
    bs[b * 32 + blk] = reds[0] + reds[1] + reds[2] + reds[3];
  }
}

// ---------------- softmax pass2: combine 32 block pairs per batch ----------
__global__ void softmax_pass2(const float* __restrict__ bm, const float* __restrict__ bs,
                              float* __restrict__ MS) {
  const int b = blockIdx.x, t = threadIdx.x;  // 64 threads
  const float m = (t < 32) ? bm[b * 32 + t] : -3.4e38f;
  float s = (t < 32) ? bs[b * 32 + t] : 0.f;
  float M = m;
  for (int o = 32; o; o >>= 1) M = fmaxf(M, __shfl_xor(M, o));
  s *= __expf(m - M);
  for (int o = 32; o; o >>= 1) s += __shfl_xor(s, o);
  if (t == 0) { MS[b * 2] = M; MS[b * 2 + 1] = 1.0f / s; }
}

// ---------------- softmax pass3: write WT bf16, fully coalesced ------------
__global__ __launch_bounds__(256) void softmax_pass3(
    const float* __restrict__ Lt, const float* __restrict__ S2, const float* __restrict__ S3,
    const float* __restrict__ b2, const float* __restrict__ b3,
    const float* __restrict__ MS, u16* __restrict__ WTh) {
  __shared__ float ls2[256], lb2[256];
  const int b = blockIdx.y, blk = blockIdx.x, t = threadIdx.x;
  ls2[t] = S2[b * 256 + t];
  lb2[t] = b2[t];
  __syncthreads();
  const float M = MS[b * 2], inv = MS[b * 2 + 1];
  const int fw0 = blk * 2048 + t * 8;
  const int d = fw0 >> 8, a0 = fw0 & 255;
  const float c1 = b3[d];
  const float c0 = S3[b * 256 + d] + 4096.f * c1;
  const long base = (long)b * 65536 + fw0;
  float4 v0 = *(const float4*)(Lt + base);
  float4 v1 = *(const float4*)(Lt + base + 4);
  float v[8] = {v0.x, v0.y, v0.z, v0.w, v1.x, v1.y, v1.z, v1.w};
  union { u16 h[8]; uint4 q; } o;
#pragma unroll
  for (int i = 0; i < 8; ++i) {
    const float vv = v[i] + lb2[a0 + i] * c0 + c1 * ls2[a0 + i];
    o.h[i] = f2b(__expf(vv - M) * inv);
  }
  *(uint4*)(WTh + base) = o.q;
}

extern "C" void kernel_launch(void* const* d_in, const int* in_sizes, int n_in,
                              void* d_out, int out_size, void* d_ws, size_t ws_size,
                              hipStream_t stream) {
  const float* x  = (const float*)d_in[0];
  const float* w1 = (const float*)d_in[1];
  const float* b1 = (const float*)d_in[2];
  const float* w2 = (const float*)d_in[3];
  const float* b2 = (const float*)d_in[4];
  const float* w3 = (const float*)d_in[5];
  const float* b3 = (const float*)d_in[6];
  float* out = (float*)d_out;

  char* ws = (char*)d_ws;
  size_t off = 0;
  auto alloc = [&](size_t bytes) {
    void* p = ws + off;
    off += (bytes + 255) & ~(size_t)255;
    return p;
  };
  const size_t BIG = 16ull * 4096 * 256 * 2;          // 32 MiB bf16
  u16* Xh   = (u16*)alloc(BIG);
  u16* Xl   = (u16*)alloc(BIG);
  u16* Xth  = (u16*)alloc(BIG);
  u16* Vth  = (u16*)alloc(BIG);
  float* Gp = (float*)alloc(8ull * 16 * 65536 * 4);   // 32 MiB split-K partials
  u16* Gh   = (u16*)alloc(16ull * 65536 * 2);
  u16* Gl   = (u16*)alloc(16ull * 65536 * 2);
  u16* T3h  = (u16*)alloc(16ull * 65536 * 2);
  u16* T3l  = (u16*)alloc(16ull * 65536 * 2);
  float* Lb = (float*)alloc(16ull * 65536 * 4);       // Lt[d][a]
  u16* WTh  = (u16*)alloc(16ull * 65536 * 2);
  u16* W1h  = (u16*)alloc(65536 * 2);
  u16* W2h  = (u16*)alloc(65536 * 2);
  u16* W2l  = (u16*)alloc(65536 * 2);
  u16* W3h  = (u16*)alloc(65536 * 2);
  u16* W3l  = (u16*)alloc(65536 * 2);
  float* xsum = (float*)alloc(16 * 256 * 4);
  float* S2   = (float*)alloc(16 * 256 * 4);
  float* S3   = (float*)alloc(16 * 256 * 4);
  float* bmx  = (float*)alloc(16 * 32 * 4);
  float* bsx  = (float*)alloc(16 * 32 * 4);
  float* MS   = (float*)alloc(32 * 4);

  hipMemsetAsync(xsum, 0, 16 * 256 * 4, stream);
  split_w_kernel<<<768, 256, 0, stream>>>(w1, w2, w3, W1h, W2h, W2l, W3h, W3l);
  prep_x_kernel<<<dim3(128, 8, 16), dim3(32, 8), 0, stream>>>(x, Xh, Xl, Xth, xsum);

  // G partials = X X^T, K=4096, split-K 8x512. M=N=256.
  gemm_tn<true, 0, false><<<dim3(4, 8, 16), 256, 0, stream>>>(
      Xh, Xl, Xh, Xl, 1048576, 1048576, 65536, 1048576,
      256, 256, 4096, 512, 2, Gp, nullptr, nullptr, nullptr);
  reduce_g_kernel<<<4096, 256, 0, stream>>>(Gp, Gh, Gl);

  // T3 = W3 * G  (G symmetric -> TN ok). M=N=K=256.
  gemm_tn<true, 1, false><<<dim3(4, 1, 16), 256, 0, stream>>>(
      W3h, W3l, Gh, Gl, 0, 65536, 65536, 0,
      256, 256, 256, 256, 2, nullptr, T3h, T3l, nullptr);
  // Lt = T3 * W2^T  ->  Lt[d][a] = logits[a][d].
  gemm_tn<true, 0, false><<<dim3(4, 1, 16), 256, 0, stream>>>(
      T3h, T3l, W2h, W2l, 65536, 0, 65536, 0,
      256, 256, 256, 256, 2, Lb, nullptr, nullptr, nullptr);

  // softmax: bias prep + 3 parallel passes (all coalesced, no spills)
  bias_prep_kernel<<<16, 512, 0, stream>>>(w2, w3, xsum, S2, S3);
  softmax_pass1<<<dim3(32, 16), 256, 0, stream>>>(Lb, S2, S3, b2, b3, bmx, bsx);
  softmax_pass2<<<16, 64, 0, stream>>>(bmx, bsx, MS);
  softmax_pass3<<<dim3(32, 16), 256, 0, stream>>>(Lb, S2, S3, b2, b3, MS, WTh);

  // Vt = Xt * W1^T + b1 (col bias over output channel). M=4096, N=256, K=256.
  gemm_tn<false, 2, true><<<dim3(64, 1, 16), 256, 0, stream>>>(
      Xth, nullptr, W1h, nullptr, 1048576, 0, 1048576, 0,
      4096, 256, 256, 256, 32, nullptr, Vth, nullptr, b1);
  // out = WT * Vt^T. M=256, N=4096, K=256 -> d_out [b][d][n].
  gemm_tn<false, 0, false><<<dim3(64, 1, 16), 256, 0, stream>>>(
      WTh, nullptr, Vth, nullptr, 65536, 1048576, 1048576, 0,
      256, 4096, 256, 256, 2, out, nullptr, nullptr, nullptr);
}

// Round 3
// 299.159 us; speedup vs baseline: 1.1928x; 1.0329x over previous
//
#include <hip/hip_runtime.h>

// GlobalChannelAttention: B=16, C=256, N=H*W=4096
//
// Pipeline (TN-form GEMMs: C[M,N] = sum_k A[m][k]*B[n][k], K contiguous):
//   1. prep:  x f32 -> Xh/Xl (bf16 hi/lo, [b][c][n]) + Xth (bf16, [b][n][c]) + xsum
//   2. Gram:  G[b] = X X^T. One 512-thr block per (batch, k-split/16) computes the
//      FULL 256x256 tile with A=B shared staging -> each X byte fetched once.
//      bf16x3, f32 partials -> reduce to G hi/lo.
//   3. T3 = W3*G (G symmetric), Lt = T3*W2^T  == logits TRANSPOSED (Lt[d][a])
//   4. global softmax (3-pass, coalesced, same-index read/write) -> WT bf16
//   5. out = (WT*W1)*X + WT*b1:  M = WT*W1T (256^3, bf16), bb = WT·b1,
//      out = M*Xt^T + bb  (row bias). V is never materialized.
//
// Precision: logit chain bf16 hi/lo x3 (err ~2^-17 rel); out chain plain bf16.

typedef unsigned short u16;
typedef __attribute__((ext_vector_type(8))) short short8;
typedef __attribute__((ext_vector_type(4))) float floatx4;

__device__ __forceinline__ u16 f2b(float f) {
  union { float f; unsigned int u; } v; v.f = f;
  unsigned int u = v.u;
  return (u16)((u + 0x7fffu + ((u >> 16) & 1u)) >> 16);  // RNE
}
__device__ __forceinline__ float b2f(u16 h) {
  union { unsigned int u; float f; } v; v.u = ((unsigned int)h) << 16;
  return v.f;
}

// ---------------- w2,w3 -> hi/lo bf16 ----------------
__global__ void split_w23_kernel(const float* __restrict__ w2, const float* __restrict__ w3,
                                 u16* __restrict__ W2h, u16* __restrict__ W2l,
                                 u16* __restrict__ W3h, u16* __restrict__ W3l) {
  int i = blockIdx.x * 256 + threadIdx.x;  // 0..131071
  int e = i & 0xffff;
  const float f = (i >> 16) ? w3[e] : w2[e];
  u16 h = f2b(f);
  if (i >> 16) { W3h[e] = h; W3l[e] = f2b(f - b2f(h)); }
  else         { W2h[e] = h; W2l[e] = f2b(f - b2f(h)); }
}

// ---------------- w1 -> bf16 transposed: W1Th[e][c] = w1[c][e] ----------------
__global__ void transpose_w1_kernel(const float* __restrict__ w1, u16* __restrict__ W1Th) {
  __shared__ float tile[32][33];
  const int c0 = blockIdx.y * 32, e0 = blockIdx.x * 32;
  const int tx = threadIdx.x, ty = threadIdx.y;  // 32x8
#pragma unroll
  for (int i = 0; i < 4; ++i)
    tile[ty + i * 8][tx] = w1[(c0 + ty + i * 8) * 256 + e0 + tx];
  __syncthreads();
#pragma unroll
  for (int i = 0; i < 4; ++i)
    W1Th[(e0 + ty + i * 8) * 256 + c0 + tx] = f2b(tile[tx][ty + i * 8]);
}

// ---------------- x prep: split + transpose + column sums ----------------
__global__ void prep_x_kernel(const float* __restrict__ x, u16* __restrict__ Xh,
                              u16* __restrict__ Xl, u16* __restrict__ Xth,
                              float* __restrict__ xsum) {
  __shared__ float tile[32][33];
  const int b = blockIdx.z, c0 = blockIdx.y * 32, n0 = blockIdx.x * 32;
  const int tx = threadIdx.x, ty = threadIdx.y;
#pragma unroll
  for (int i = 0; i < 4; ++i) {
    int c = c0 + ty + i * 8;
    long gi = ((long)(b * 256 + c)) * 4096 + n0 + tx;
    float v = x[gi];
    tile[ty + i * 8][tx] = v;
    u16 h = f2b(v);
    Xh[gi] = h;
    Xl[gi] = f2b(v - b2f(h));
  }
  __syncthreads();
#pragma unroll
  for (int i = 0; i < 4; ++i) {
    int n = n0 + ty + i * 8;
    Xth[((long)(b * 4096 + n)) * 256 + c0 + tx] = f2b(tile[tx][ty + i * 8]);
  }
  if (ty == 0) {
    float s = 0.f;
#pragma unroll
    for (int j = 0; j < 32; ++j) s += tile[tx][j];
    atomicAdd(&xsum[b * 256 + c0 + tx], s);
  }
}

// ---------------- Gram: one block = full 256x256 for (batch, split) -----------
// 512 threads / 8 waves; wave (wm in {0,128}, wn in {0,64,128,192}) does 128x64.
// A and B fragments both come from the SAME staged 256-row k-slab.
__global__ __launch_bounds__(512, 2) void gram_kernel(
    const u16* __restrict__ Xh, const u16* __restrict__ Xl, float* __restrict__ Gp) {
  constexpr int LR = 40;  // +8 pad: 2-way bank aliasing only (free per m136)
  __shared__ u16 lH[256 * LR], lL[256 * LR];
  const int b = blockIdx.x >> 4, s = blockIdx.x & 15;
  const u16* Hb = Xh + (long)b * 1048576 + s * 256;
  const u16* Lo = Xl + (long)b * 1048576 + s * 256;
  const int t = threadIdx.x;
  const int lane = t & 63, wave = t >> 6;
  const int quad = lane >> 4, l16 = lane & 15;
  const int wm = (wave & 1) * 128, wn = (wave >> 1) * 64;
  floatx4 acc[8][4] = {};
  for (int kb = 0; kb < 256; kb += 32) {
    __syncthreads();
#pragma unroll
    for (int h = 0; h < 2; ++h) {
      const int item = t + h * 512;
      const int r = item >> 2, qc = (item & 3) * 8;
      *(uint4*)(lH + r * LR + qc) = *(const uint4*)(Hb + (long)r * 4096 + kb + qc);
      *(uint4*)(lL + r * LR + qc) = *(const uint4*)(Lo + (long)r * 4096 + kb + qc);
    }
    __syncthreads();
#pragma unroll
    for (int j = 0; j < 4; ++j) {
      const short8 bh = *(const short8*)(lH + (wn + j * 16 + l16) * LR + quad * 8);
      const short8 bl = *(const short8*)(lL + (wn + j * 16 + l16) * LR + quad * 8);
#pragma unroll
      for (int i = 0; i < 8; ++i) {
        const short8 ah = *(const short8*)(lH + (wm + i * 16 + l16) * LR + quad * 8);
        const short8 al = *(const short8*)(lL + (wm + i * 16 + l16) * LR + quad * 8);
        acc[i][j] = __builtin_amdgcn_mfma_f32_16x16x32_bf16(ah, bh, acc[i][j], 0, 0, 0);
        acc[i][j] = __builtin_amdgcn_mfma_f32_16x16x32_bf16(ah, bl, acc[i][j], 0, 0, 0);
        acc[i][j] = __builtin_amdgcn_mfma_f32_16x16x32_bf16(al, bh, acc[i][j], 0, 0, 0);
      }
    }
  }
  float* G = Gp + ((long)b * 16 + s) * 65536;
#pragma unroll
  for (int i = 0; i < 8; ++i) {
    const int row0 = wm + i * 16 + quad * 4;
#pragma unroll
    for (int j = 0; j < 4; ++j) {
      const int col = wn + j * 16 + l16;
#pragma unroll
      for (int r = 0; r < 4; ++r)
        G[(long)(row0 + r) * 256 + col] = acc[i][j][r];
    }
  }
}

// ---------------- Gram split-K reduction + hi/lo split ----------------
__global__ void reduce_g_kernel(const float* __restrict__ Gp, u16* __restrict__ Gh,
                                u16* __restrict__ Gl) {
  const long e = (long)blockIdx.x * 256 + threadIdx.x;  // over 16*65536
  const long base = ((e >> 16) << 20) + (e & 65535);    // b*16*65536 + idx
  float s = 0.f;
#pragma unroll
  for (int i = 0; i < 16; ++i) s += Gp[base + (long)i * 65536];
  u16 h = f2b(s);
  Gh[e] = h;
  Gl[e] = f2b(s - b2f(h));
}

// ---------------- TN GEMM core: 128x128 tile, BK=32, 4 waves ----------------
// EPI: 0 = f32 store, 1 = bf16 hi/lo store, 2 = bf16 hi store
template <bool X3, int EPI, bool ROWBIAS>
__global__ __launch_bounds__(256) void gemm_tn(
    const u16* __restrict__ Ah, const u16* __restrict__ Al,
    const u16* __restrict__ Bh, const u16* __restrict__ Bl,
    long aBatch, long bBatch, long oBatch,
    int M, int N, int K, int tilesM,
    float* __restrict__ outF, u16* __restrict__ outH, u16* __restrict__ outL,
    const float* __restrict__ bias) {
  constexpr int LR = 40;
  __shared__ u16 smem[(X3 ? 4 : 2) * 128 * LR];
  u16* lAh = smem;
  u16* lBh = smem + 128 * LR;
  u16* lAl = X3 ? (smem + 2 * 128 * LR) : nullptr;
  u16* lBl = X3 ? (smem + 3 * 128 * LR) : nullptr;

  const int b = blockIdx.z;
  const int tm = blockIdx.x % tilesM, tn = blockIdx.x / tilesM;
  const u16* Ahb = Ah + (long)b * aBatch;
  const u16* Bhb = Bh + (long)b * bBatch;
  const u16* Alb = X3 ? (Al + (long)b * aBatch) : nullptr;
  const u16* Blb = X3 ? (Bl + (long)b * bBatch) : nullptr;

  const int t = threadIdx.x;
  const int lane = t & 63, wave = t >> 6;
  const int quad = lane >> 4, l16 = lane & 15;
  const int wm = (wave & 1) * 64, wn = (wave >> 1) * 64;

  const int srow = t >> 2;
  const int scol = (t & 3) * 8;

  floatx4 acc[4][4] = {};

  for (int kk = 0; kk < K; kk += 32) {
    __syncthreads();
#pragma unroll
    for (int h = 0; h < 2; ++h) {
      const int r = srow + h * 64;
      *(uint4*)(lAh + r * LR + scol) = *(const uint4*)(Ahb + (long)(tm * 128 + r) * K + kk + scol);
      *(uint4*)(lBh + r * LR + scol) = *(const uint4*)(Bhb + (long)(tn * 128 + r) * K + kk + scol);
      if (X3) {
        *(uint4*)(lAl + r * LR + scol) = *(const uint4*)(Alb + (long)(tm * 128 + r) * K + kk + scol);
        *(uint4*)(lBl + r * LR + scol) = *(const uint4*)(Blb + (long)(tn * 128 + r) * K + kk + scol);
      }
    }
    __syncthreads();
    short8 afh[4], bfh[4], afl[4], bfl[4];
#pragma unroll
    for (int i = 0; i < 4; ++i) {
      afh[i] = *(const short8*)(lAh + (wm + i * 16 + l16) * LR + quad * 8);
      bfh[i] = *(const short8*)(lBh + (wn + i * 16 + l16) * LR + quad * 8);
      if (X3) {
        afl[i] = *(const short8*)(lAl + (wm + i * 16 + l16) * LR + quad * 8);
        bfl[i] = *(const short8*)(lBl + (wn + i * 16 + l16) * LR + quad * 8);
      }
    }
#pragma unroll
    for (int i = 0; i < 4; ++i)
#pragma unroll
      for (int j = 0; j < 4; ++j) {
        acc[i][j] = __builtin_amdgcn_mfma_f32_16x16x32_bf16(afh[i], bfh[j], acc[i][j], 0, 0, 0);
        if (X3) {
          acc[i][j] = __builtin_amdgcn_mfma_f32_16x16x32_bf16(afh[i], bfl[j], acc[i][j], 0, 0, 0);
          acc[i][j] = __builtin_amdgcn_mfma_f32_16x16x32_bf16(afl[i], bfh[j], acc[i][j], 0, 0, 0);
        }
      }
  }

  const long obase = (long)b * oBatch;
#pragma unroll
  for (int i = 0; i < 4; ++i) {
    const int mb = tm * 128 + wm + i * 16 + quad * 4;
#pragma unroll
    for (int j = 0; j < 4; ++j) {
      const int n = tn * 128 + wn + j * 16 + l16;
#pragma unroll
      for (int r = 0; r < 4; ++r) {
        const float bv = ROWBIAS ? bias[b * 256 + mb + r] : 0.0f;
        const float v = acc[i][j][r] + bv;
        const long idx = obase + (long)(mb + r) * N + n;
        if (EPI == 0) {
          outF[idx] = v;
        } else if (EPI == 1) {
          u16 h = f2b(v);
          outH[idx] = h;
          outL[idx] = f2b(v - b2f(h));
        } else {
          outH[idx] = f2b(v);
        }
      }
    }
  }
}

// ---------------- bias prep: s2[b][a]=w2[a,:]·xsum[b], s3 likewise --------
__global__ __launch_bounds__(512) void bias_prep_kernel(
    const float* __restrict__ w2, const float* __restrict__ w3,
    const float* __restrict__ xsum, float* __restrict__ S2, float* __restrict__ S3) {
  __shared__ float xs[256];
  const int b = blockIdx.x, t = threadIdx.x;
  if (t < 256) xs[t] = xsum[b * 256 + t];
  __syncthreads();
  const float* wm = (t < 256) ? w2 : w3;
  const int a = t & 255;
  float s = 0.f;
#pragma unroll 4
  for (int c = 0; c < 256; ++c) s += wm[a * 256 + c] * xs[c];
  if (t < 256) S2[b * 256 + a] = s;
  else         S3[b * 256 + a] = s;
}

// ---------------- softmax pass1: per-block (max, sumexp) ------------------
__global__ __launch_bounds__(256) void softmax_pass1(
    const float* __restrict__ Lt, const float* __restrict__ S2, const float* __restrict__ S3,
    const float* __restrict__ b2, const float* __restrict__ b3,
    float* __restrict__ bm, float* __restrict__ bs) {
  __shared__ float ls2[256], lb2[256];
  __shared__ float redm[4], reds[4];
  const int b = blockIdx.y, blk = blockIdx.x, t = threadIdx.x;
  ls2[t] = S2[b * 256 + t];
  lb2[t] = b2[t];
  __syncthreads();
  const int fw0 = blk * 2048 + t * 8;
  const int d = fw0 >> 8, a0 = fw0 & 255;
  const float c1 = b3[d];
  const float c0 = S3[b * 256 + d] + 4096.f * c1;
  const long base = (long)b * 65536 + fw0;
  float4 v0 = *(const float4*)(Lt + base);
  float4 v1 = *(const float4*)(Lt + base + 4);
  float v[8] = {v0.x, v0.y, v0.z, v0.w, v1.x, v1.y, v1.z, v1.w};
  float m = -3.4e38f;
#pragma unroll
  for (int i = 0; i < 8; ++i) {
    v[i] += lb2[a0 + i] * c0 + c1 * ls2[a0 + i];
    m = fmaxf(m, v[i]);
  }
  for (int o = 32; o; o >>= 1) m = fmaxf(m, __shfl_xor(m, o));
  const int wid = t >> 6, lane = t & 63;
  if (lane == 0) redm[wid] = m;
  __syncthreads();
  const float bmax = fmaxf(fmaxf(redm[0], redm[1]), fmaxf(redm[2], redm[3]));
  float s = 0.f;
#pragma unroll
  for (int i = 0; i < 8; ++i) s += __expf(v[i] - bmax);
  for (int o = 32; o; o >>= 1) s += __shfl_xor(s, o);
  if (lane == 0) reds[wid] = s;
  __syncthreads();
  if (t == 0) {
    bm[b * 32 + blk] = bmax;
    bs[b * 32 + blk] = reds[0] + reds[1] + reds[2] + reds[3];
  }
}

// ---------------- softmax pass2: combine ----------
__global__ void softmax_pass2(const float* __restrict__ bm, const float* __restrict__ bs,
                              float* __restrict__ MS) {
  const int b = blockIdx.x, t = threadIdx.x;  // 64 threads
  const float m = (t < 32) ? bm[b * 32 + t] : -3.4e38f;
  float s = (t < 32) ? bs[b * 32 + t] : 0.f;
  float M = m;
  for (int o = 32; o; o >>= 1) M = fmaxf(M, __shfl_xor(M, o));
  s *= __expf(m - M);
  for (int o = 32; o; o >>= 1) s += __shfl_xor(s, o);
  if (t == 0) { MS[b * 2] = M; MS[b * 2 + 1] = 1.0f / s; }
}

// ---------------- softmax pass3: write WT bf16 ------------
__global__ __launch_bounds__(256) void softmax_pass3(
    const float* __restrict__ Lt, const float* __restrict__ S2, const float* __restrict__ S3,
    const float* __restrict__ b2, const float* __restrict__ b3,
    const float* __restrict__ MS, u16* __restrict__ WTh) {
  __shared__ float ls2[256], lb2[256];
  const int b = blockIdx.y, blk = blockIdx.x, t = threadIdx.x;
  ls2[t] = S2[b * 256 + t];
  lb2[t] = b2[t];
  __syncthreads();
  const float M = MS[b * 2], inv = MS[b * 2 + 1];
  const int fw0 = blk * 2048 + t * 8;
  const int d = fw0 >> 8, a0 = fw0 & 255;
  const float c1 = b3[d];
  const float c0 = S3[b * 256 + d] + 4096.f * c1;
  const long base = (long)b * 65536 + fw0;
  float4 v0 = *(const float4*)(Lt + base);
  float4 v1 = *(const float4*)(Lt + base + 4);
  float v[8] = {v0.x, v0.y, v0.z, v0.w, v1.x, v1.y, v1.z, v1.w};
  union { u16 h[8]; uint4 q; } o;
#pragma unroll
  for (int i = 0; i < 8; ++i) {
    const float vv = v[i] + lb2[a0 + i] * c0 + c1 * ls2[a0 + i];
    o.h[i] = f2b(__expf(vv - M) * inv);
  }
  *(uint4*)(WTh + base) = o.q;
}

// ---------------- bb[b][d] = sum_c weight[c][d]*b1[c] ----------------
__global__ void bb_kernel(const u16* __restrict__ WTh, const float* __restrict__ b1,
                          float* __restrict__ bb) {
  const int b = blockIdx.x, d = threadIdx.x;
  const u16* row = WTh + (long)b * 65536 + d * 256;
  float s = 0.f;
#pragma unroll 4
  for (int c = 0; c < 256; ++c) s += b2f(row[c]) * b1[c];
  bb[b * 256 + d] = s;
}

extern "C" void kernel_launch(void* const* d_in, const int* in_sizes, int n_in,
                              void* d_out, int out_size, void* d_ws, size_t ws_size,
                              hipStream_t stream) {
  const float* x  = (const float*)d_in[0];
  const float* w1 = (const float*)d_in[1];
  const float* b1 = (const float*)d_in[2];
  const float* w2 = (const float*)d_in[3];
  const float* b2 = (const float*)d_in[4];
  const float* w3 = (const float*)d_in[5];
  const float* b3 = (const float*)d_in[6];
  float* out = (float*)d_out;

  char* ws = (char*)d_ws;
  size_t off = 0;
  auto alloc = [&](size_t bytes) {
    void* p = ws + off;
    off += (bytes + 255) & ~(size_t)255;
    return p;
  };
  const size_t BIG = 16ull * 4096 * 256 * 2;           // 32 MiB bf16
  u16* Xh   = (u16*)alloc(BIG);
  u16* Xl   = (u16*)alloc(BIG);
  u16* Xth  = (u16*)alloc(BIG);
  float* Gp = (float*)alloc(16ull * 16 * 65536 * 4);   // 64 MiB split-K partials
  u16* Gh   = (u16*)alloc(16ull * 65536 * 2);
  u16* Gl   = (u16*)alloc(16ull * 65536 * 2);
  u16* T3h  = (u16*)alloc(16ull * 65536 * 2);
  u16* T3l  = (u16*)alloc(16ull * 65536 * 2);
  float* Lb = (float*)alloc(16ull * 65536 * 4);        // Lt[d][a]
  u16* WTh  = (u16*)alloc(16ull * 65536 * 2);
  u16* Mh   = (u16*)alloc(16ull * 65536 * 2);
  u16* W1Th = (u16*)alloc(65536 * 2);
  u16* W2h  = (u16*)alloc(65536 * 2);
  u16* W2l  = (u16*)alloc(65536 * 2);
  u16* W3h  = (u16*)alloc(65536 * 2);
  u16* W3l  = (u16*)alloc(65536 * 2);
  float* xsum = (float*)alloc(16 * 256 * 4);
  float* S2   = (float*)alloc(16 * 256 * 4);
  float* S3   = (float*)alloc(16 * 256 * 4);
  float* bmx  = (float*)alloc(16 * 32 * 4);
  float* bsx  = (float*)alloc(16 * 32 * 4);
  float* MS   = (float*)alloc(32 * 4);
  float* bb   = (float*)alloc(16 * 256 * 4);

  hipMemsetAsync(xsum, 0, 16 * 256 * 4, stream);
  transpose_w1_kernel<<<dim3(8, 8), dim3(32, 8), 0, stream>>>(w1, W1Th);
  split_w23_kernel<<<512, 256, 0, stream>>>(w2, w3, W2h, W2l, W3h, W3l);
  prep_x_kernel<<<dim3(128, 8, 16), dim3(32, 8), 0, stream>>>(x, Xh, Xl, Xth, xsum);

  // Gram partials: grid 256 = 16 batches x 16 k-splits, each block full 256x256.
  gram_kernel<<<256, 512, 0, stream>>>(Xh, Xl, Gp);
  reduce_g_kernel<<<4096, 256, 0, stream>>>(Gp, Gh, Gl);

  // T3 = W3 * G (G symmetric -> TN ok). M=N=K=256.
  gemm_tn<true, 1, false><<<dim3(4, 1, 16), 256, 0, stream>>>(
      W3h, W3l, Gh, Gl, 0, 65536, 65536,
      256, 256, 256, 2, nullptr, T3h, T3l, nullptr);
  // Lt = T3 * W2^T  ->  Lt[d][a] = logits[a][d].
  gemm_tn<true, 0, false><<<dim3(4, 1, 16), 256, 0, stream>>>(
      T3h, T3l, W2h, W2l, 65536, 0, 65536,
      256, 256, 256, 2, Lb, nullptr, nullptr, nullptr);

  // softmax: bias prep + 3 parallel passes
  bias_prep_kernel<<<16, 512, 0, stream>>>(w2, w3, xsum, S2, S3);
  softmax_pass1<<<dim3(32, 16), 256, 0, stream>>>(Lb, S2, S3, b2, b3, bmx, bsx);
  softmax_pass2<<<16, 64, 0, stream>>>(bmx, bsx, MS);
  softmax_pass3<<<dim3(32, 16), 256, 0, stream>>>(Lb, S2, S3, b2, b3, MS, WTh);

  // out-chain: M = WT*W1T (bf16), bb = WT·b1, out = M*Xt^T + bb
  bb_kernel<<<16, 256, 0, stream>>>(WTh, b1, bb);
  gemm_tn<false, 2, false><<<dim3(4, 1, 16), 256, 0, stream>>>(
      WTh, nullptr, W1Th, nullptr, 65536, 0, 65536,
      256, 256, 256, 2, nullptr, Mh, nullptr, nullptr);
  // out[d][n] = sum_e M[d][e] x[e][n] + bb[d]. M=256, N=4096, K=256.
  gemm_tn<false, 0, true><<<dim3(64, 1, 16), 256, 0, stream>>>(
      Mh, nullptr, Xth, nullptr, 65536, 1048576, 1048576,
      256, 4096, 256, 2, out, nullptr, nullptr, bb);
}

// Round 4
// 253.024 us; speedup vs baseline: 1.4103x; 1.1823x over previous
//
#include <hip/hip_runtime.h>

// GlobalChannelAttention: B=16, C=256, H*W=4096
//
// Pipeline (TN-form GEMMs: C[M,N] = sum_k A[m][k]*B[n][k], K contiguous):
//   1. prep_w: w1 -> W1Th (bf16 transposed), w2/w3 -> hi/lo bf16
//   2. gram: G[b] = X X^T read DIRECTLY from x f32 (hi/lo split in staging),
//      one 512-thr block per (batch, n-split/16) computes full 256x256;
//      xsum folded into staging. f32 partials -> reduce to G hi/lo.
//   3. T3 = W3*G (G symmetric), Lt = T3*W2^T == logits TRANSPOSED (Lt[d][a])
//   4. global softmax (pass1 + fused combine/write pass3, coalesced) -> WT bf16
//   5. out = (WT*W1)*X + WT*b1:  Mh = WT*W1T (bf16), bb = WT·b1,
//      out = Mh*X^T + bb -- B operand read straight from x f32 with in-LDS
//      transpose (XOR-swizzled, conflict-free). No X copy is ever materialized.
//
// Precision: logit chain bf16 hi/lo x3 (err ~2^-17 rel); out chain plain bf16.

typedef unsigned short u16;
typedef __attribute__((ext_vector_type(8))) short short8;
typedef __attribute__((ext_vector_type(4))) float floatx4;

__device__ __forceinline__ u16 f2b(float f) {
  union { float f; unsigned int u; } v; v.f = f;
  unsigned int u = v.u;
  return (u16)((u + 0x7fffu + ((u >> 16) & 1u)) >> 16);  // RNE
}
__device__ __forceinline__ float b2f(u16 h) {
  union { unsigned int u; float f; } v; v.u = ((unsigned int)h) << 16;
  return v.f;
}

// ---------------- merged W prep: transpose w1 + split w2/w3 ----------------
__global__ __launch_bounds__(256) void prep_w_kernel(
    const float* __restrict__ w1, const float* __restrict__ w2, const float* __restrict__ w3,
    u16* __restrict__ W1Th, u16* __restrict__ W2h, u16* __restrict__ W2l,
    u16* __restrict__ W3h, u16* __restrict__ W3l) {
  const int blk = blockIdx.x, t = threadIdx.x;
  if (blk < 64) {  // W1Th[e][c] = w1[c][e]
    __shared__ float tile[32][33];
    const int e0 = (blk & 7) * 32, c0 = (blk >> 3) * 32;
    const int tx = t & 31, ty = t >> 5;
#pragma unroll
    for (int i = 0; i < 4; ++i)
      tile[ty + i * 8][tx] = w1[(c0 + ty + i * 8) * 256 + e0 + tx];
    __syncthreads();
#pragma unroll
    for (int i = 0; i < 4; ++i)
      W1Th[(e0 + ty + i * 8) * 256 + c0 + tx] = f2b(tile[tx][ty + i * 8]);
  } else {
    const int i = (blk - 64) * 256 + t;  // 0..131071
    const int e = i & 0xffff;
    const float f = (i >> 16) ? w3[e] : w2[e];
    u16 h = f2b(f);
    if (i >> 16) { W3h[e] = h; W3l[e] = f2b(f - b2f(h)); }
    else         { W2h[e] = h; W2l[e] = f2b(f - b2f(h)); }
  }
}

// ---------------- Gram from raw x: full 256x256 per (batch, split) ---------
// 512 threads / 8 waves; wave (wm in {0,128}, wn in {0,64,128,192}) does 128x64.
// Stages x f32 -> hi/lo bf16 LDS; A and B fragments share the staged slab.
// xsum accumulated during staging (quad shuffle + 1 atomic per row per block).
__global__ __launch_bounds__(512, 2) void gram_kernel(
    const float* __restrict__ x, float* __restrict__ Gp, float* __restrict__ xsum) {
  constexpr int LR = 40;  // +8 pad: 2-way bank aliasing only (free per m136)
  __shared__ u16 lH[256 * LR], lL[256 * LR];
  const int b = blockIdx.x >> 4, s = blockIdx.x & 15;
  const float* Xb = x + (long)b * 1048576 + s * 256;
  const int t = threadIdx.x;
  const int lane = t & 63, wave = t >> 6;
  const int quad = lane >> 4, l16 = lane & 15;
  const int wm = (wave & 1) * 128, wn = (wave >> 1) * 64;
  floatx4 acc[8][4] = {};
  float xacc[2] = {0.f, 0.f};
  for (int kb = 0; kb < 256; kb += 32) {
    __syncthreads();
#pragma unroll
    for (int h = 0; h < 2; ++h) {
      const int item = t + h * 512;
      const int r = item >> 2, qc = (item & 3) * 8;
      const float4 f0 = *(const float4*)(Xb + (long)r * 4096 + kb + qc);
      const float4 f1 = *(const float4*)(Xb + (long)r * 4096 + kb + qc + 4);
      const float f[8] = {f0.x, f0.y, f0.z, f0.w, f1.x, f1.y, f1.z, f1.w};
      union { u16 h8[8]; uint4 q; } uh, ul;
#pragma unroll
      for (int i = 0; i < 8; ++i) {
        const u16 hi = f2b(f[i]);
        uh.h8[i] = hi;
        ul.h8[i] = f2b(f[i] - b2f(hi));
        xacc[h] += f[i];
      }
      *(uint4*)(lH + r * LR + qc) = uh.q;
      *(uint4*)(lL + r * LR + qc) = ul.q;
    }
    __syncthreads();
#pragma unroll
    for (int j = 0; j < 4; ++j) {
      const short8 bh = *(const short8*)(lH + (wn + j * 16 + l16) * LR + quad * 8);
      const short8 bl = *(const short8*)(lL + (wn + j * 16 + l16) * LR + quad * 8);
#pragma unroll
      for (int i = 0; i < 8; ++i) {
        const short8 ah = *(const short8*)(lH + (wm + i * 16 + l16) * LR + quad * 8);
        const short8 al = *(const short8*)(lL + (wm + i * 16 + l16) * LR + quad * 8);
        acc[i][j] = __builtin_amdgcn_mfma_f32_16x16x32_bf16(ah, bh, acc[i][j], 0, 0, 0);
        acc[i][j] = __builtin_amdgcn_mfma_f32_16x16x32_bf16(ah, bl, acc[i][j], 0, 0, 0);
        acc[i][j] = __builtin_amdgcn_mfma_f32_16x16x32_bf16(al, bh, acc[i][j], 0, 0, 0);
      }
    }
  }
  // xsum: lanes t..t+3 (quad group) share row (item>>2)
#pragma unroll
  for (int h = 0; h < 2; ++h) {
    float v = xacc[h];
    v += __shfl_xor(v, 1);
    v += __shfl_xor(v, 2);
    if ((t & 3) == 0) atomicAdd(&xsum[b * 256 + ((t + h * 512) >> 2)], v);
  }
  float* G = Gp + ((long)b * 16 + s) * 65536;
#pragma unroll
  for (int i = 0; i < 8; ++i) {
    const int row0 = wm + i * 16 + quad * 4;
#pragma unroll
    for (int j = 0; j < 4; ++j) {
      const int col = wn + j * 16 + l16;
#pragma unroll
      for (int r = 0; r < 4; ++r)
        G[(long)(row0 + r) * 256 + col] = acc[i][j][r];
    }
  }
}

// ---------------- Gram split-K reduction + hi/lo split ----------------
__global__ void reduce_g_kernel(const float* __restrict__ Gp, u16* __restrict__ Gh,
                                u16* __restrict__ Gl) {
  const long e = (long)blockIdx.x * 256 + threadIdx.x;  // over 16*65536
  const long base = ((e >> 16) << 20) + (e & 65535);    // b*16*65536 + idx
  float s = 0.f;
#pragma unroll
  for (int i = 0; i < 16; ++i) s += Gp[base + (long)i * 65536];
  u16 h = f2b(s);
  Gh[e] = h;
  Gl[e] = f2b(s - b2f(h));
}

// ---------------- TN GEMM core: 128x128 tile, BK=32, 4 waves ----------------
// EPI: 0 = f32 store, 1 = bf16 hi/lo store, 2 = bf16 hi store
template <bool X3, int EPI>
__global__ __launch_bounds__(256) void gemm_tn(
    const u16* __restrict__ Ah, const u16* __restrict__ Al,
    const u16* __restrict__ Bh, const u16* __restrict__ Bl,
    long aBatch, long bBatch, long oBatch,
    int M, int N, int K, int tilesM,
    float* __restrict__ outF, u16* __restrict__ outH, u16* __restrict__ outL) {
  constexpr int LR = 40;
  __shared__ u16 smem[(X3 ? 4 : 2) * 128 * LR];
  u16* lAh = smem;
  u16* lBh = smem + 128 * LR;
  u16* lAl = X3 ? (smem + 2 * 128 * LR) : nullptr;
  u16* lBl = X3 ? (smem + 3 * 128 * LR) : nullptr;

  const int b = blockIdx.z;
  const int tm = blockIdx.x % tilesM, tn = blockIdx.x / tilesM;
  const u16* Ahb = Ah + (long)b * aBatch;
  const u16* Bhb = Bh + (long)b * bBatch;
  const u16* Alb = X3 ? (Al + (long)b * aBatch) : nullptr;
  const u16* Blb = X3 ? (Bl + (long)b * bBatch) : nullptr;

  const int t = threadIdx.x;
  const int lane = t & 63, wave = t >> 6;
  const int quad = lane >> 4, l16 = lane & 15;
  const int wm = (wave & 1) * 64, wn = (wave >> 1) * 64;
  const int srow = t >> 2, scol = (t & 3) * 8;

  floatx4 acc[4][4] = {};

  for (int kk = 0; kk < K; kk += 32) {
    __syncthreads();
#pragma unroll
    for (int h = 0; h < 2; ++h) {
      const int r = srow + h * 64;
      *(uint4*)(lAh + r * LR + scol) = *(const uint4*)(Ahb + (long)(tm * 128 + r) * K + kk + scol);
      *(uint4*)(lBh + r * LR + scol) = *(const uint4*)(Bhb + (long)(tn * 128 + r) * K + kk + scol);
      if (X3) {
        *(uint4*)(lAl + r * LR + scol) = *(const uint4*)(Alb + (long)(tm * 128 + r) * K + kk + scol);
        *(uint4*)(lBl + r * LR + scol) = *(const uint4*)(Blb + (long)(tn * 128 + r) * K + kk + scol);
      }
    }
    __syncthreads();
    short8 afh[4], bfh[4], afl[4], bfl[4];
#pragma unroll
    for (int i = 0; i < 4; ++i) {
      afh[i] = *(const short8*)(lAh + (wm + i * 16 + l16) * LR + quad * 8);
      bfh[i] = *(const short8*)(lBh + (wn + i * 16 + l16) * LR + quad * 8);
      if (X3) {
        afl[i] = *(const short8*)(lAl + (wm + i * 16 + l16) * LR + quad * 8);
        bfl[i] = *(const short8*)(lBl + (wn + i * 16 + l16) * LR + quad * 8);
      }
    }
#pragma unroll
    for (int i = 0; i < 4; ++i)
#pragma unroll
      for (int j = 0; j < 4; ++j) {
        acc[i][j] = __builtin_amdgcn_mfma_f32_16x16x32_bf16(afh[i], bfh[j], acc[i][j], 0, 0, 0);
        if (X3) {
          acc[i][j] = __builtin_amdgcn_mfma_f32_16x16x32_bf16(afh[i], bfl[j], acc[i][j], 0, 0, 0);
          acc[i][j] = __builtin_amdgcn_mfma_f32_16x16x32_bf16(afl[i], bfh[j], acc[i][j], 0, 0, 0);
        }
      }
  }

  const long obase = (long)b * oBatch;
#pragma unroll
  for (int i = 0; i < 4; ++i) {
    const int mb = tm * 128 + wm + i * 16 + quad * 4;
#pragma unroll
    for (int j = 0; j < 4; ++j) {
      const int n = tn * 128 + wn + j * 16 + l16;
#pragma unroll
      for (int r = 0; r < 4; ++r) {
        const float v = acc[i][j][r];
        const long idx = obase + (long)(mb + r) * N + n;
        if (EPI == 0) {
          outF[idx] = v;
        } else if (EPI == 1) {
          u16 h = f2b(v);
          outH[idx] = h;
          outL[idx] = f2b(v - b2f(h));
        } else {
          outH[idx] = f2b(v);
        }
      }
    }
  }
}

// ---------------- out = Mh * X^T + bb : B operand straight from x f32 -------
// 128x128 tile, BK=32. B staged with in-LDS transpose, XOR-swizzled e-blocks.
__global__ __launch_bounds__(256) void gemm_out(
    const u16* __restrict__ Mh, const float* __restrict__ x,
    const float* __restrict__ bb, float* __restrict__ out) {
  constexpr int LR = 40;
  __shared__ u16 lA[128 * LR], lB[128 * LR];
  const int b = blockIdx.z;
  const int tm = blockIdx.x & 1, tn = blockIdx.x >> 1;  // tilesM=2, tilesN=32
  const u16* Ab = Mh + (long)b * 65536;
  const float* Xb = x + (long)b * 1048576 + tn * 128;
  const int t = threadIdx.x;
  const int lane = t & 63, wave = t >> 6;
  const int quad = lane >> 4, l16 = lane & 15;
  const int wm = (wave & 1) * 64, wn = (wave >> 1) * 64;
  const int er = t >> 3;          // 0..31 e-row
  const int noff = (t & 7) * 16;  // n offset
  floatx4 acc[4][4] = {};
  for (int kk = 0; kk < 256; kk += 32) {
    __syncthreads();
#pragma unroll
    for (int h = 0; h < 2; ++h) {
      const int r = (t >> 2) + h * 64;
      *(uint4*)(lA + r * LR + (t & 3) * 8) =
          *(const uint4*)(Ab + (long)(tm * 128 + r) * 256 + kk + (t & 3) * 8);
    }
#pragma unroll
    for (int i4 = 0; i4 < 4; ++i4) {
      const float4 f = *(const float4*)(Xb + (long)(kk + er) * 4096 + noff + i4 * 4);
      const float fv[4] = {f.x, f.y, f.z, f.w};
#pragma unroll
      for (int i = 0; i < 4; ++i) {
        const int nl = noff + i4 * 4 + i;
        const int sb = (er >> 3) ^ ((nl >> 4) & 3);  // swizzle e-block
        lB[nl * LR + sb * 8 + (er & 7)] = f2b(fv[i]);
      }
    }
    __syncthreads();
    short8 af[4], bf[4];
#pragma unroll
    for (int i = 0; i < 4; ++i) {
      af[i] = *(const short8*)(lA + (wm + i * 16 + l16) * LR + quad * 8);
      const int n = wn + i * 16 + l16;
      const int rb = quad ^ ((n >> 4) & 3);
      bf[i] = *(const short8*)(lB + n * LR + rb * 8);
    }
#pragma unroll
    for (int i = 0; i < 4; ++i)
#pragma unroll
      for (int j = 0; j < 4; ++j)
        acc[i][j] = __builtin_amdgcn_mfma_f32_16x16x32_bf16(af[i], bf[j], acc[i][j], 0, 0, 0);
  }
  const long obase = (long)b * 1048576;
#pragma unroll
  for (int i = 0; i < 4; ++i) {
    const int mb = tm * 128 + wm + i * 16 + quad * 4;
#pragma unroll
    for (int j = 0; j < 4; ++j) {
      const int n = tn * 128 + wn + j * 16 + l16;
#pragma unroll
      for (int r = 0; r < 4; ++r)
        out[obase + (long)(mb + r) * 4096 + n] = acc[i][j][r] + bb[b * 256 + mb + r];
    }
  }
}

// ---------------- bias prep: s2[b][a]=w2[a,:]·xsum[b], s3 likewise --------
__global__ __launch_bounds__(512) void bias_prep_kernel(
    const float* __restrict__ w2, const float* __restrict__ w3,
    const float* __restrict__ xsum, float* __restrict__ S2, float* __restrict__ S3) {
  __shared__ float xs[256];
  const int b = blockIdx.x, t = threadIdx.x;
  if (t < 256) xs[t] = xsum[b * 256 + t];
  __syncthreads();
  const float* wm = (t < 256) ? w2 : w3;
  const int a = t & 255;
  float s = 0.f;
#pragma unroll 4
  for (int c = 0; c < 256; ++c) s += wm[a * 256 + c] * xs[c];
  if (t < 256) S2[b * 256 + a] = s;
  else         S3[b * 256 + a] = s;
}

// ---------------- softmax pass1: per-block (max, sumexp) ------------------
__global__ __launch_bounds__(256) void softmax_pass1(
    const float* __restrict__ Lt, const float* __restrict__ S2, const float* __restrict__ S3,
    const float* __restrict__ b2, const float* __restrict__ b3,
    float* __restrict__ bm, float* __restrict__ bs) {
  __shared__ float ls2[256], lb2[256];
  __shared__ float redm[4], reds[4];
  const int b = blockIdx.y, blk = blockIdx.x, t = threadIdx.x;
  ls2[t] = S2[b * 256 + t];
  lb2[t] = b2[t];
  __syncthreads();
  const int fw0 = blk * 2048 + t * 8;
  const int d = fw0 >> 8, a0 = fw0 & 255;
  const float c1 = b3[d];
  const float c0 = S3[b * 256 + d] + 4096.f * c1;
  const long base = (long)b * 65536 + fw0;
  float4 v0 = *(const float4*)(Lt + base);
  float4 v1 = *(const float4*)(Lt + base + 4);
  float v[8] = {v0.x, v0.y, v0.z, v0.w, v1.x, v1.y, v1.z, v1.w};
  float m = -3.4e38f;
#pragma unroll
  for (int i = 0; i < 8; ++i) {
    v[i] += lb2[a0 + i] * c0 + c1 * ls2[a0 + i];
    m = fmaxf(m, v[i]);
  }
  for (int o = 32; o; o >>= 1) m = fmaxf(m, __shfl_xor(m, o));
  const int wid = t >> 6, lane = t & 63;
  if (lane == 0) redm[wid] = m;
  __syncthreads();
  const float bmax = fmaxf(fmaxf(redm[0], redm[1]), fmaxf(redm[2], redm[3]));
  float s = 0.f;
#pragma unroll
  for (int i = 0; i < 8; ++i) s += __expf(v[i] - bmax);
  for (int o = 32; o; o >>= 1) s += __shfl_xor(s, o);
  if (lane == 0) reds[wid] = s;
  __syncthreads();
  if (t == 0) {
    bm[b * 32 + blk] = bmax;
    bs[b * 32 + blk] = reds[0] + reds[1] + reds[2] + reds[3];
  }
}

// ------- softmax pass3: inline combine + write WT bf16 (coalesced) ---------
__global__ __launch_bounds__(256) void softmax_pass3(
    const float* __restrict__ Lt, const float* __restrict__ S2, const float* __restrict__ S3,
    const float* __restrict__ b2, const float* __restrict__ b3,
    const float* __restrict__ bm, const float* __restrict__ bs,
    u16* __restrict__ WTh) {
  __shared__ float ls2[256], lb2[256];
  __shared__ float sM, sInv;
  const int b = blockIdx.y, blk = blockIdx.x, t = threadIdx.x;
  if (t < 64) {  // combine 32 block pairs (wave 0 only)
    const float m = (t < 32) ? bm[b * 32 + t] : -3.4e38f;
    float s = (t < 32) ? bs[b * 32 + t] : 0.f;
    float M = m;
    for (int o = 32; o; o >>= 1) M = fmaxf(M, __shfl_xor(M, o));
    s *= __expf(m - M);
    for (int o = 32; o; o >>= 1) s += __shfl_xor(s, o);
    if (t == 0) { sM = M; sInv = 1.0f / s; }
  }
  ls2[t] = S2[b * 256 + t];
  lb2[t] = b2[t];
  __syncthreads();
  const float M = sM, inv = sInv;
  const int fw0 = blk * 2048 + t * 8;
  const int d = fw0 >> 8, a0 = fw0 & 255;
  const float c1 = b3[d];
  const float c0 = S3[b * 256 + d] + 4096.f * c1;
  const long base = (long)b * 65536 + fw0;
  float4 v0 = *(const float4*)(Lt + base);
  float4 v1 = *(const float4*)(Lt + base + 4);
  float v[8] = {v0.x, v0.y, v0.z, v0.w, v1.x, v1.y, v1.z, v1.w};
  union { u16 h[8]; uint4 q; } o;
#pragma unroll
  for (int i = 0; i < 8; ++i) {
    const float vv = v[i] + lb2[a0 + i] * c0 + c1 * ls2[a0 + i];
    o.h[i] = f2b(__expf(vv - M) * inv);
  }
  *(uint4*)(WTh + base) = o.q;
}

// ---------------- bb[b][d] = sum_c weight[c][d]*b1[c] ----------------
__global__ void bb_kernel(const u16* __restrict__ WTh, const float* __restrict__ b1,
                          float* __restrict__ bb) {
  const int b = blockIdx.x, d = threadIdx.x;
  const u16* row = WTh + (long)b * 65536 + d * 256;
  float s = 0.f;
#pragma unroll 4
  for (int c = 0; c < 256; ++c) s += b2f(row[c]) * b1[c];
  bb[b * 256 + d] = s;
}

extern "C" void kernel_launch(void* const* d_in, const int* in_sizes, int n_in,
                              void* d_out, int out_size, void* d_ws, size_t ws_size,
                              hipStream_t stream) {
  const float* x  = (const float*)d_in[0];
  const float* w1 = (const float*)d_in[1];
  const float* b1 = (const float*)d_in[2];
  const float* w2 = (const float*)d_in[3];
  const float* b2 = (const float*)d_in[4];
  const float* w3 = (const float*)d_in[5];
  const float* b3 = (const float*)d_in[6];
  float* out = (float*)d_out;

  char* ws = (char*)d_ws;
  size_t off = 0;
  auto alloc = [&](size_t bytes) {
    void* p = ws + off;
    off += (bytes + 255) & ~(size_t)255;
    return p;
  };
  float* Gp = (float*)alloc(16ull * 16 * 65536 * 4);   // 64 MiB split-K partials
  u16* Gh   = (u16*)alloc(16ull * 65536 * 2);
  u16* Gl   = (u16*)alloc(16ull * 65536 * 2);
  u16* T3h  = (u16*)alloc(16ull * 65536 * 2);
  u16* T3l  = (u16*)alloc(16ull * 65536 * 2);
  float* Lb = (float*)alloc(16ull * 65536 * 4);        // Lt[d][a]
  u16* WTh  = (u16*)alloc(16ull * 65536 * 2);
  u16* Mh   = (u16*)alloc(16ull * 65536 * 2);
  u16* W1Th = (u16*)alloc(65536 * 2);
  u16* W2h  = (u16*)alloc(65536 * 2);
  u16* W2l  = (u16*)alloc(65536 * 2);
  u16* W3h  = (u16*)alloc(65536 * 2);
  u16* W3l  = (u16*)alloc(65536 * 2);
  float* xsum = (float*)alloc(16 * 256 * 4);
  float* S2   = (float*)alloc(16 * 256 * 4);
  float* S3   = (float*)alloc(16 * 256 * 4);
  float* bmx  = (float*)alloc(16 * 32 * 4);
  float* bsx  = (float*)alloc(16 * 32 * 4);
  float* bb   = (float*)alloc(16 * 256 * 4);

  hipMemsetAsync(xsum, 0, 16 * 256 * 4, stream);
  prep_w_kernel<<<576, 256, 0, stream>>>(w1, w2, w3, W1Th, W2h, W2l, W3h, W3l);

  // Gram partials straight from x: 16 batches x 16 n-splits, full 256x256 each.
  gram_kernel<<<256, 512, 0, stream>>>(x, Gp, xsum);
  reduce_g_kernel<<<4096, 256, 0, stream>>>(Gp, Gh, Gl);

  // T3 = W3 * G (G symmetric -> TN ok). M=N=K=256.
  gemm_tn<true, 1><<<dim3(4, 1, 16), 256, 0, stream>>>(
      W3h, W3l, Gh, Gl, 0, 65536, 65536,
      256, 256, 256, 2, nullptr, T3h, T3l);
  // Lt = T3 * W2^T  ->  Lt[d][a] = logits[a][d].
  gemm_tn<true, 0><<<dim3(4, 1, 16), 256, 0, stream>>>(
      T3h, T3l, W2h, W2l, 65536, 0, 65536,
      256, 256, 256, 2, Lb, nullptr, nullptr);

  // softmax: bias prep + pass1 + fused combine/write pass3
  bias_prep_kernel<<<16, 512, 0, stream>>>(w2, w3, xsum, S2, S3);
  softmax_pass1<<<dim3(32, 16), 256, 0, stream>>>(Lb, S2, S3, b2, b3, bmx, bsx);
  softmax_pass3<<<dim3(32, 16), 256, 0, stream>>>(Lb, S2, S3, b2, b3, bmx, bsx, WTh);

  // out-chain: Mh = WT*W1T (bf16), bb = WT·b1, out = Mh*X^T + bb
  bb_kernel<<<16, 256, 0, stream>>>(WTh, b1, bb);
  gemm_tn<false, 2><<<dim3(4, 1, 16), 256, 0, stream>>>(
      WTh, nullptr, W1Th, nullptr, 65536, 0, 65536,
      256, 256, 256, 2, nullptr, Mh, nullptr);
  gemm_out<<<dim3(64, 1, 16), 256, 0, stream>>>(Mh, x, bb, out);
}